// Round 5
// baseline (802.635 us; speedup 1.0000x reference)
//
#include <hip/hip_runtime.h>

#define NEGV (-1000000000.0f)

typedef __attribute__((ext_vector_type(8))) short sh8;
typedef __attribute__((ext_vector_type(4))) short sh4;
typedef __attribute__((ext_vector_type(8))) __bf16 bf16x8;
typedef __attribute__((ext_vector_type(4))) float f32x4;

__device__ __forceinline__ float b2f(unsigned short u) {
  unsigned v = ((unsigned)u) << 16;
  return __builtin_bit_cast(float, v);
}
__device__ __forceinline__ unsigned short f2b(float f) {
  unsigned x = __builtin_bit_cast(unsigned, f);
  unsigned r = (x + 0x7fffu + ((x >> 16) & 1u)) >> 16;
  return (unsigned short)r;
}
__device__ __forceinline__ void g2l16(const void* g, void* l) {
  __builtin_amdgcn_global_load_lds((const __attribute__((address_space(1))) unsigned int*)g,
                                   (__attribute__((address_space(3))) unsigned int*)l, 16, 0, 0);
}
__device__ __forceinline__ f32x4 mfma16(bf16x8 a, bf16x8 b, f32x4 c) {
  return __builtin_amdgcn_mfma_f32_16x16x32_bf16(a, b, c, 0, 0, 0);
}
__device__ __forceinline__ float fast_tanh(float x) {
  x = fminf(fmaxf(x, -15.f), 15.f);
  float e = __expf(2.f * x);
  return (e - 1.f) / (e + 1.f);
}

// ---------------- conversion kernels ----------------
__global__ void cvt_bf16(const float* __restrict__ src, unsigned short* __restrict__ dst, int n4) {
  int i = blockIdx.x * blockDim.x + threadIdx.x;
  int stride = gridDim.x * blockDim.x;
  for (; i < n4; i += stride) {
    float4 v = ((const float4*)src)[i];
    sh4 o;
    o[0] = (short)f2b(v.x); o[1] = (short)f2b(v.y);
    o[2] = (short)f2b(v.z); o[3] = (short)f2b(v.w);
    ((sh4*)dst)[i] = o;
  }
}

// dst[n][k] = bf16(src[k][n]) for 1024x1024
__global__ void tcvt(const float* __restrict__ src, unsigned short* __restrict__ dst) {
  __shared__ float tile[64][65];
  int bx = blockIdx.x, by = blockIdx.y;
  int tx = threadIdx.x & 63, ty = threadIdx.x >> 6;
#pragma unroll
  for (int i = 0; i < 16; ++i) {
    int r = i * 4 + ty;
    tile[r][tx] = src[(size_t)(by * 64 + r) * 1024 + bx * 64 + tx];
  }
  __syncthreads();
#pragma unroll
  for (int i = 0; i < 16; ++i) {
    int r = i * 4 + ty;
    dst[(size_t)(bx * 64 + r) * 1024 + by * 64 + tx] = f2b(tile[tx][r]);
  }
}

// ---------------- 256x256 bf16 MFMA GEMM, K=1024, ring-4 LDS ----------------
// Register-double-buffered fragment pipeline: at iter kt we (1) stage kt+3,
// (2) issue 12 ds_read_b128 for tile kt+1 into frag set NXT, (3) MFMA on set
// CUR (its reads are 12 DS ops old -> counted lgkm wait ~free; new reads run
// under MFMA), (4) vmcnt(4) + ONE barrier. Bank swizzle as round 4 (verified
// 0 conflicts). EPI 0: row-major+bias. EPI 1: fused QKV. EPI 2: his-score.
template<int EPI>
__global__ __launch_bounds__(512, 1)
void gemm256(const unsigned short* __restrict__ A, const unsigned short* __restrict__ Bt,
             int nbx,
             const float* __restrict__ b0, const float* __restrict__ b1,
             const float* __restrict__ b2,
             unsigned short* __restrict__ O0, unsigned short* __restrict__ O1,
             unsigned short* __restrict__ O2,
             const float* __restrict__ aq, const float* __restrict__ wa,
             float* __restrict__ sc)
{
  __shared__ char lds[131072];
  const int tid = threadIdx.x;
  const int w = tid >> 6, l = tid & 63;
  const int wm = w >> 2, wn = w & 3;
  const int lr = l & 15, g = l >> 4;
  const int swz = (lr >> 1) & 3;

  // bijective XCD swizzle (gridDim.x % 8 == 0 for all our shapes)
  const int wg = blockIdx.x;
  const int cpx = gridDim.x >> 3;
  const int wgid = (wg & 7) * cpx + (wg >> 3);
  const int bx = wgid % nbx, by = wgid / nbx;
  const size_t m0 = (size_t)by * 256;
  const int n0 = bx * 256;

  f32x4 acc[8][4] = {};
  bf16x8 fa[2][8], fb[2][4];

  // staging: thread covers row tid>>2 of a 128-row half; source chunk pre-swizzled
  const int srow = tid >> 2;
  const int sk = (((tid & 3) ^ ((tid >> 3) & 3)) * 8);
  const unsigned short* gA = A + (m0 + srow) * 1024 + sk;
  const unsigned short* gB = Bt + ((size_t)n0 + srow) * 1024 + sk;
  char* const sbase = lds + w * 1024;  // wave-uniform; HW adds lane*16

  // compute-side swizzled LDS byte offsets (within a 32KB buffer)
  const int aoff = (wm * 128 + lr) * 64 + ((g ^ swz) * 16);          // + i*1024 per frag
  const int boff = 16384 + (wn * 64 + lr) * 64 + ((g ^ swz) * 16);   // + j*1024 per frag

  auto stageAB = [&](int kt) {
    const unsigned short* a = gA + kt * 32;
    const unsigned short* b = gB + kt * 32;
    char* base = sbase + ((kt & 3) << 15);
    g2l16(a, base);
    g2l16(a + 128 * 1024, base + 8192);
    g2l16(b, base + 16384);
    g2l16(b + 128 * 1024, base + 24576);
  };

  // ---- prologue: stage tiles 0,1,2; wait for 0 and 1; load cur <- buf0 ----
  stageAB(0); stageAB(1); stageAB(2);
  asm volatile("s_waitcnt vmcnt(4)" ::: "memory");   // buf0,buf1 resident; buf2 in flight
  __builtin_amdgcn_s_barrier();
  {
    const char* p0 = lds;
#pragma unroll
    for (int j = 0; j < 4; ++j) fb[0][j] = *(const bf16x8*)(p0 + boff + j * 1024);
#pragma unroll
    for (int i = 0; i < 8; ++i) fa[0][i] = *(const bf16x8*)(p0 + aoff + i * 1024);
  }
  __builtin_amdgcn_sched_barrier(0);

#define GITER(KTV, CUR, NXT)                                                   \
  {                                                                            \
    const int kt_ = (KTV);                                                     \
    if (kt_ < 29) stageAB(kt_ + 3);                                            \
    if (kt_ < 31) {                                                            \
      const char* pn_ = lds + (((kt_ + 1) & 3) << 15);                         \
      _Pragma("unroll")                                                        \
      for (int j = 0; j < 4; ++j)                                              \
        fb[NXT][j] = *(const bf16x8*)(pn_ + boff + j * 1024);                  \
      _Pragma("unroll")                                                        \
      for (int i = 0; i < 8; ++i)                                              \
        fa[NXT][i] = *(const bf16x8*)(pn_ + aoff + i * 1024);                  \
    }                                                                          \
    __builtin_amdgcn_sched_barrier(0);                                         \
    __builtin_amdgcn_s_setprio(1);                                             \
    _Pragma("unroll")                                                          \
    for (int i = 0; i < 8; ++i)                                                \
      _Pragma("unroll")                                                        \
      for (int j = 0; j < 4; ++j)                                              \
        acc[i][j] = mfma16(fa[CUR][i], fb[CUR][j], acc[i][j]);                 \
    __builtin_amdgcn_s_setprio(0);                                             \
    if (kt_ < 29) { asm volatile("s_waitcnt vmcnt(4)" ::: "memory"); }         \
    else if (kt_ == 29) { asm volatile("s_waitcnt vmcnt(0)" ::: "memory"); }   \
    if (kt_ < 31) __builtin_amdgcn_s_barrier();                                \
  }

#pragma unroll 1
  for (int kk = 0; kk < 28; kk += 2) {
    GITER(kk, 0, 1)
    GITER(kk + 1, 1, 0)
  }
  GITER(28, 0, 1)
  GITER(29, 1, 0)
  GITER(30, 0, 1)
  GITER(31, 1, 0)
#undef GITER

  // ======== epilogue ========
  if (EPI == 0) {
#pragma unroll
    for (int j = 0; j < 4; ++j) {
      int col = n0 + wn * 64 + j * 16 + lr;
      float bv = b0[col];
#pragma unroll
      for (int i = 0; i < 8; ++i) {
        size_t rowb = m0 + wm * 128 + i * 16 + g * 4;
#pragma unroll
        for (int r = 0; r < 4; ++r)
          O0[(rowb + r) * 1024 + col] = f2b(acc[i][j][r] + bv);
      }
    }
  } else if (EPI == 1) {
#pragma unroll
    for (int j = 0; j < 4; ++j) {
      int col3 = n0 + wn * 64 + j * 16 + lr;
      int part = col3 >> 10, c = col3 & 1023;
      float bv = (part == 0) ? b0[c] : (part == 1) ? b1[c] : b2[c];
      if (part < 2) {
        unsigned short* O = part == 0 ? O0 : O1;
#pragma unroll
        for (int i = 0; i < 8; ++i) {
          size_t rowb = m0 + wm * 128 + i * 16 + g * 4;
#pragma unroll
          for (int r = 0; r < 4; ++r)
            O[(rowb + r) * 1024 + c] = f2b(acc[i][j][r] + bv);
        }
      } else {  // v: transposed layout vT[(b*4+h)*256 + d][512] = v[b, l, h, d]
        int h = c >> 8, d = c & 255;
#pragma unroll
        for (int i = 0; i < 8; ++i) {
          size_t row = m0 + wm * 128 + i * 16 + g * 4;
          int bb = (int)(row >> 9), ll = (int)(row & 511);
          size_t base = ((size_t)(bb * 4 + h) * 256 + d) * 512 + ll;
#pragma unroll
          for (int r = 0; r < 4; ++r)
            O2[base + r] = f2b(acc[i][j][r] + bv);
        }
      }
    }
  } else {
    const int bb = (int)(m0 >> 11);
#pragma unroll
    for (int i = 0; i < 8; ++i) {
      float rp[4] = {0.f, 0.f, 0.f, 0.f};
#pragma unroll
      for (int j = 0; j < 4; ++j) {
        int col = n0 + wn * 64 + j * 16 + lr;
        float wav = wa[col];
        float aqv = aq[bb * 1024 + col];
#pragma unroll
        for (int r = 0; r < 4; ++r)
          rp[r] += wav * fast_tanh(acc[i][j][r] + aqv);
      }
#pragma unroll
      for (int off = 1; off < 16; off <<= 1)
#pragma unroll
        for (int r = 0; r < 4; ++r)
          rp[r] += __shfl_xor(rp[r], off, 64);
      if (lr == 0) {
        size_t rowb = m0 + wm * 128 + i * 16 + g * 4;
#pragma unroll
        for (int r = 0; r < 4; ++r)
          atomicAdd(&sc[rowb + r], rp[r]);
      }
    }
  }
}

// ---------------- fused attention (register softmax, 34.3KB LDS) ----------------
__global__ __launch_bounds__(256, 4)
void attn_kernel(const unsigned short* __restrict__ q, const unsigned short* __restrict__ k,
                 const unsigned short* __restrict__ vT, const float* __restrict__ seq_mask,
                 unsigned short* __restrict__ ctx, float* __restrict__ attn_out)
{
  __shared__ char smem[34304];
  unsigned short* Qs = (unsigned short*)smem;
  unsigned short* Ps = (unsigned short*)smem;
  float* redm = (float*)(smem + 33280);
  float* reds = (float*)(smem + 33792);
  const int t = threadIdx.x, w = t >> 6, l = t & 63;
  const int lr = l & 15, g = l >> 4, lk8 = g * 8;
  const int wg = blockIdx.x;
  const int wgid = (wg & 7) * 256 + (wg >> 3);
  const int qt = wgid & 15, bh = wgid >> 4;
  const int h = bh & 3, b = bh >> 2;
  const int l0 = qt * 32;

  for (int idx = t; idx < 32 * 32; idx += 256) {
    int r = idx >> 5, ch = (idx & 31) * 8;
    *(sh8*)&Qs[r * 264 + ch] =
        *(const sh8*)&q[((size_t)(b * 512 + l0 + r)) * 1024 + h * 256 + ch];
  }
  __syncthreads();

  f32x4 accs[2][8] = {};
  const unsigned short* kbase = k + ((size_t)b * 512) * 1024 + h * 256;
#pragma unroll
  for (int ds = 0; ds < 8; ++ds) {
    int d0 = ds * 32;
    bf16x8 a0 = *(const bf16x8*)&Qs[lr * 264 + d0 + lk8];
    bf16x8 a1 = *(const bf16x8*)&Qs[(16 + lr) * 264 + d0 + lk8];
#pragma unroll
    for (int j = 0; j < 8; ++j) {
      int kj = w * 128 + j * 16 + lr;
      bf16x8 bb = *(const bf16x8*)&kbase[(size_t)kj * 1024 + d0 + lk8];
      accs[0][j] = mfma16(a0, bb, accs[0][j]);
      accs[1][j] = mfma16(a1, bb, accs[1][j]);
    }
  }

#pragma unroll
  for (int j = 0; j < 8; ++j) {
    int col = w * 128 + j * 16 + lr;
    float mv = seq_mask[b * 512 + col];
    bool msk = (mv == 0.f);
#pragma unroll
    for (int i = 0; i < 2; ++i)
#pragma unroll
      for (int r = 0; r < 4; ++r)
        accs[i][j][r] = msk ? NEGV : accs[i][j][r] * 0.0625f;
  }

  float mx[2][4], sm[2][4];
#pragma unroll
  for (int i = 0; i < 2; ++i)
#pragma unroll
    for (int r = 0; r < 4; ++r) {
      float m = accs[i][0][r];
#pragma unroll
      for (int j = 1; j < 8; ++j) m = fmaxf(m, accs[i][j][r]);
      mx[i][r] = m;
    }
#pragma unroll
  for (int off = 1; off < 16; off <<= 1)
#pragma unroll
    for (int i = 0; i < 2; ++i)
#pragma unroll
      for (int r = 0; r < 4; ++r)
        mx[i][r] = fmaxf(mx[i][r], __shfl_xor(mx[i][r], off, 64));
  if (lr == 0) {
#pragma unroll
    for (int i = 0; i < 2; ++i)
#pragma unroll
      for (int r = 0; r < 4; ++r)
        redm[w * 32 + i * 16 + g * 4 + r] = mx[i][r];
  }
  __syncthreads();
#pragma unroll
  for (int i = 0; i < 2; ++i)
#pragma unroll
    for (int r = 0; r < 4; ++r) {
      int row = i * 16 + g * 4 + r;
      mx[i][r] = fmaxf(fmaxf(redm[row], redm[32 + row]),
                       fmaxf(redm[64 + row], redm[96 + row]));
      sm[i][r] = 0.f;
    }

#pragma unroll
  for (int i = 0; i < 2; ++i)
#pragma unroll
    for (int j = 0; j < 8; ++j)
#pragma unroll
      for (int r = 0; r < 4; ++r) {
        float p = __expf(accs[i][j][r] - mx[i][r]);
        accs[i][j][r] = p;
        sm[i][r] += p;
      }
#pragma unroll
  for (int off = 1; off < 16; off <<= 1)
#pragma unroll
    for (int i = 0; i < 2; ++i)
#pragma unroll
      for (int r = 0; r < 4; ++r)
        sm[i][r] += __shfl_xor(sm[i][r], off, 64);
  if (lr == 0) {
#pragma unroll
    for (int i = 0; i < 2; ++i)
#pragma unroll
      for (int r = 0; r < 4; ++r)
        reds[w * 32 + i * 16 + g * 4 + r] = sm[i][r];
  }
  __syncthreads();
#pragma unroll
  for (int i = 0; i < 2; ++i)
#pragma unroll
    for (int r = 0; r < 4; ++r) {
      int row = i * 16 + g * 4 + r;
      float s = reds[row] + reds[32 + row] + reds[64 + row] + reds[96 + row];
      sm[i][r] = 1.f / s;
    }

#pragma unroll
  for (int i = 0; i < 2; ++i)
#pragma unroll
    for (int j = 0; j < 8; ++j) {
      int col = w * 128 + j * 16 + lr;
#pragma unroll
      for (int r = 0; r < 4; ++r) {
        int row = i * 16 + g * 4 + r;
        float pn = accs[i][j][r] * sm[i][r];
        Ps[row * 520 + col] = f2b(pn);
        if (h == 0)
          attn_out[((size_t)(b * 512 + l0 + row)) * 512 + col] = pn;
      }
    }
  __syncthreads();

  f32x4 acco[2][4] = {};
  const unsigned short* vbase = vT + ((size_t)(b * 4 + h)) * 256 * 512;
#pragma unroll
  for (int ks = 0; ks < 16; ++ks) {
    int kj0 = ks * 32;
    bf16x8 a0 = *(const bf16x8*)&Ps[lr * 520 + kj0 + lk8];
    bf16x8 a1 = *(const bf16x8*)&Ps[(16 + lr) * 520 + kj0 + lk8];
#pragma unroll
    for (int j = 0; j < 4; ++j) {
      int d = w * 64 + j * 16 + lr;
      bf16x8 bb = *(const bf16x8*)&vbase[(size_t)d * 512 + kj0 + lk8];
      acco[0][j] = mfma16(a0, bb, acco[0][j]);
      acco[1][j] = mfma16(a1, bb, acco[1][j]);
    }
  }
#pragma unroll
  for (int i = 0; i < 2; ++i)
#pragma unroll
    for (int j = 0; j < 4; ++j) {
      int col = w * 64 + j * 16 + lr;
#pragma unroll
      for (int r = 0; r < 4; ++r) {
        int row = i * 16 + g * 4 + r;
        ctx[((size_t)(b * 512 + l0 + row)) * 1024 + h * 256 + col] = f2b(acco[i][j][r]);
      }
    }
}

// ---------------- LN + masked mean over L ----------------
__global__ __launch_bounds__(256)
void ln_mean(const unsigned short* __restrict__ sa, const float* __restrict__ g,
             const float* __restrict__ bt, const float* __restrict__ mask,
             float* __restrict__ poi_sum)
{
  const int b = blockIdx.y, ch = blockIdx.x;
  const int t = threadIdx.x, w = t >> 6, l = t & 63;
  float gg[16], bb[16];
#pragma unroll
  for (int j = 0; j < 16; ++j) { gg[j] = g[l * 16 + j]; bb[j] = bt[l * 16 + j]; }
  float accv[16];
#pragma unroll
  for (int j = 0; j < 16; ++j) accv[j] = 0.f;
  for (int rr = 0; rr < 16; ++rr) {
    int row = ch * 64 + w * 16 + rr;
    const unsigned short* rp = sa + ((size_t)(b * 512 + row)) * 1024 + l * 16;
    float x[16];
    sh8 v0 = *(const sh8*)rp;
    sh8 v1 = *(const sh8*)(rp + 8);
#pragma unroll
    for (int j = 0; j < 8; ++j) {
      x[j] = b2f((unsigned short)v0[j]);
      x[8 + j] = b2f((unsigned short)v1[j]);
    }
    float s = 0.f, s2 = 0.f;
#pragma unroll
    for (int j = 0; j < 16; ++j) { s += x[j]; s2 += x[j] * x[j]; }
#pragma unroll
    for (int off = 1; off < 64; off <<= 1) {
      s += __shfl_xor(s, off, 64);
      s2 += __shfl_xor(s2, off, 64);
    }
    float mean = s * (1.f / 1024.f);
    float var = s2 * (1.f / 1024.f) - mean * mean;
    float rinv = rsqrtf(var + 1e-5f);
    float mk = mask[b * 512 + row];
#pragma unroll
    for (int j = 0; j < 16; ++j) accv[j] += ((x[j] - mean) * rinv * gg[j] + bb[j]) * mk;
  }
#pragma unroll
  for (int j = 0; j < 16; ++j) atomicAdd(&poi_sum[b * 1024 + l * 16 + j], accv[j]);
}

__global__ void finalize_poi(const float* __restrict__ ps, float* __restrict__ poi) {
  int i = blockIdx.x * 256 + threadIdx.x;
  if (i < 32 * 1024) poi[i] = ps[i] * (1.f / 512.f);
}

__global__ __launch_bounds__(256)
void gemv32(const float* __restrict__ in, const float* __restrict__ W, float* __restrict__ out)
{
  const int b = blockIdx.y;
  const int n = blockIdx.x * 256 + threadIdx.x;
  const float* ib = in + b * 1024;
  float acc = 0.f;
  for (int d = 0; d < 1024; d += 4) {
    acc += ib[d]     * W[(size_t)d * 1024 + n]
         + ib[d + 1] * W[(size_t)(d + 1) * 1024 + n]
         + ib[d + 2] * W[(size_t)(d + 2) * 1024 + n]
         + ib[d + 3] * W[(size_t)(d + 3) * 1024 + n];
  }
  out[b * 1024 + n] = acc;
}

__global__ __launch_bounds__(256)
void softmax_his(float* __restrict__ sc, const float* __restrict__ mask)
{
  __shared__ float red[4];
  const int b = blockIdx.x, t = threadIdx.x, w = t >> 6, l = t & 63;
  float v[8];
  float mx = -3.0e38f;
#pragma unroll
  for (int i = 0; i < 8; ++i) {
    int kk = t + i * 256;
    float s = (mask[b * 2048 + kk] == 0.f) ? NEGV : sc[b * 2048 + kk];
    v[i] = s;
    mx = fmaxf(mx, s);
  }
#pragma unroll
  for (int off = 1; off < 64; off <<= 1) mx = fmaxf(mx, __shfl_xor(mx, off, 64));
  if (l == 0) red[w] = mx;
  __syncthreads();
  mx = fmaxf(fmaxf(red[0], red[1]), fmaxf(red[2], red[3]));
  float sum = 0.f;
#pragma unroll
  for (int i = 0; i < 8; ++i) { v[i] = __expf(v[i] - mx); sum += v[i]; }
#pragma unroll
  for (int off = 1; off < 64; off <<= 1) sum += __shfl_xor(sum, off, 64);
  __syncthreads();
  if (l == 0) red[w] = sum;
  __syncthreads();
  sum = red[0] + red[1] + red[2] + red[3];
  float inv = 1.f / sum;
#pragma unroll
  for (int i = 0; i < 8; ++i) sc[b * 2048 + t + i * 256] = v[i] * inv;
}

__global__ __launch_bounds__(256)
void hw_kernel(const float* __restrict__ aw, const unsigned short* __restrict__ his,
               float* __restrict__ hw)
{
  const int b = blockIdx.y, kc = blockIdx.x, t = threadIdx.x;
  const int cb = t * 4;
  float a0 = 0.f, a1 = 0.f, a2 = 0.f, a3 = 0.f;
  for (int kk = 0; kk < 256; ++kk) {
    int k = kc * 256 + kk;
    float wg = aw[b * 2048 + k];
    sh4 vv = *(const sh4*)&his[((size_t)(b * 2048 + k)) * 1024 + cb];
    a0 += wg * b2f((unsigned short)vv[0]);
    a1 += wg * b2f((unsigned short)vv[1]);
    a2 += wg * b2f((unsigned short)vv[2]);
    a3 += wg * b2f((unsigned short)vv[3]);
  }
  atomicAdd(&hw[b * 1024 + cb + 0], a0);
  atomicAdd(&hw[b * 1024 + cb + 1], a1);
  atomicAdd(&hw[b * 1024 + cb + 2], a2);
  atomicAdd(&hw[b * 1024 + cb + 3], a3);
}

__global__ __launch_bounds__(256)
void final_kernel(const float* __restrict__ aa_out, const float* __restrict__ g,
                  const float* __restrict__ bt, const float* __restrict__ poi,
                  float* __restrict__ out)
{
  __shared__ float r1[4], r2[4];
  const int b = blockIdx.x, t = threadIdx.x, w = t >> 6, l = t & 63;
  float x[4];
#pragma unroll
  for (int j = 0; j < 4; ++j) x[j] = aa_out[b * 1024 + t * 4 + j];
  float s = 0.f, s2 = 0.f;
#pragma unroll
  for (int j = 0; j < 4; ++j) { s += x[j]; s2 += x[j] * x[j]; }
#pragma unroll
  for (int off = 1; off < 64; off <<= 1) {
    s += __shfl_xor(s, off, 64);
    s2 += __shfl_xor(s2, off, 64);
  }
  if (l == 0) { r1[w] = s; r2[w] = s2; }
  __syncthreads();
  s = r1[0] + r1[1] + r1[2] + r1[3];
  s2 = r2[0] + r2[1] + r2[2] + r2[3];
  float mean = s * (1.f / 1024.f);
  float var = s2 * (1.f / 1024.f) - mean * mean;
  float rinv = rsqrtf(var + 1e-5f);
#pragma unroll
  for (int j = 0; j < 4; ++j) {
    int c = t * 4 + j;
    float lnv = (x[j] - mean) * rinv * g[c] + bt[c];
    float pv = poi[b * 1024 + c];
    out[b * 2048 + c] = pv;
    out[b * 2048 + 1024 + c] = pv + lnv;
  }
}

// ---------------- host launch ----------------
extern "C" void kernel_launch(void* const* d_in, const int* in_sizes, int n_in,
                              void* d_out, int out_size, void* d_ws, size_t ws_size,
                              hipStream_t stream)
{
  const float* seq_emb  = (const float*)d_in[0];
  const float* seq_mask = (const float*)d_in[1];
  const float* his_emb  = (const float*)d_in[2];
  const float* his_mask = (const float*)d_in[3];
  const float* sa_wq = (const float*)d_in[4];
  const float* sa_bq = (const float*)d_in[5];
  const float* sa_wk = (const float*)d_in[6];
  const float* sa_bk = (const float*)d_in[7];
  const float* sa_wv = (const float*)d_in[8];
  const float* sa_bv = (const float*)d_in[9];
  const float* sa_wo = (const float*)d_in[10];
  const float* sa_bo = (const float*)d_in[11];
  const float* sn_g  = (const float*)d_in[12];
  const float* sn_b  = (const float*)d_in[13];
  const float* aa_wq = (const float*)d_in[14];
  const float* aa_wk = (const float*)d_in[15];
  const float* aa_wv = (const float*)d_in[16];
  const float* aa_wo = (const float*)d_in[17];
  const float* aa_wa = (const float*)d_in[18];
  const float* ln_g  = (const float*)d_in[19];
  const float* ln_b  = (const float*)d_in[20];
  float* out = (float*)d_out;

  char* p = (char*)d_ws;
  size_t off = 0;
  auto alloc = [&](size_t bytes) -> void* {
    void* r = p + off;
    off += (bytes + 255) & ~(size_t)255;
    return r;
  };
  unsigned short* seqb = (unsigned short*)alloc((size_t)16384 * 1024 * 2);
  unsigned short* hisb = (unsigned short*)alloc((size_t)65536 * 1024 * 2);
  unsigned short* wcat = (unsigned short*)alloc((size_t)3072 * 1024 * 2);
  unsigned short* woT  = (unsigned short*)alloc((size_t)1024 * 1024 * 2);
  unsigned short* awkT = (unsigned short*)alloc((size_t)1024 * 1024 * 2);
  unsigned short* qb   = (unsigned short*)alloc((size_t)16384 * 1024 * 2);
  unsigned short* kb   = (unsigned short*)alloc((size_t)16384 * 1024 * 2);
  unsigned short* vTb  = (unsigned short*)alloc((size_t)16384 * 1024 * 2);
  unsigned short* ctxb = (unsigned short*)alloc((size_t)16384 * 1024 * 2);
  unsigned short* saob = (unsigned short*)alloc((size_t)16384 * 1024 * 2);
  float* poi_sum = (float*)alloc((size_t)32 * 1024 * 4);
  float* poi     = (float*)alloc((size_t)32 * 1024 * 4);
  float* aqb     = (float*)alloc((size_t)32 * 1024 * 4);
  float* ascore  = (float*)alloc((size_t)32 * 2048 * 4);
  float* hwb     = (float*)alloc((size_t)32 * 1024 * 4);
  float* actx    = (float*)alloc((size_t)32 * 1024 * 4);
  float* aaout   = (float*)alloc((size_t)32 * 1024 * 4);
  if (off > ws_size) return;

  hipMemsetAsync(poi_sum, 0, (size_t)32 * 1024 * 4, stream);
  hipMemsetAsync(ascore, 0, (size_t)32 * 2048 * 4, stream);
  hipMemsetAsync(hwb, 0, (size_t)32 * 1024 * 4, stream);

  cvt_bf16<<<2048, 256, 0, stream>>>(seq_emb, seqb, 16384 * 1024 / 4);
  cvt_bf16<<<2048, 256, 0, stream>>>(his_emb, hisb, 65536 * 1024 / 4);
  dim3 tg(16, 16);
  tcvt<<<tg, 256, 0, stream>>>(sa_wq, wcat);
  tcvt<<<tg, 256, 0, stream>>>(sa_wk, wcat + (size_t)1024 * 1024);
  tcvt<<<tg, 256, 0, stream>>>(sa_wv, wcat + (size_t)2048 * 1024);
  tcvt<<<tg, 256, 0, stream>>>(sa_wo, woT);
  tcvt<<<tg, 256, 0, stream>>>(aa_wk, awkT);

  // fused QKV: M=16384, N=3072 -> 64 x 12 = 768 blocks
  gemm256<1><<<768, 512, 0, stream>>>(seqb, wcat, 12, sa_bq, sa_bk, sa_bv,
                                      qb, kb, vTb, nullptr, nullptr, nullptr);

  attn_kernel<<<2048, 256, 0, stream>>>(qb, kb, vTb, seq_mask, ctxb, out + 65536);

  // sa_out: M=16384, N=1024 -> 64 x 4 = 256 blocks
  gemm256<0><<<256, 512, 0, stream>>>(ctxb, woT, 4, sa_bo, nullptr, nullptr,
                                      saob, nullptr, nullptr, nullptr, nullptr, nullptr);
  ln_mean<<<dim3(8, 32), 256, 0, stream>>>(saob, sn_g, sn_b, seq_mask, poi_sum);
  finalize_poi<<<128, 256, 0, stream>>>(poi_sum, poi);
  gemv32<<<dim3(4, 32), 256, 0, stream>>>(poi, aa_wq, aqb);

  // his scores: M=65536, N=1024 -> 256 x 4 = 1024 blocks
  gemm256<2><<<1024, 512, 0, stream>>>(hisb, awkT, 4, nullptr, nullptr, nullptr,
                                       nullptr, nullptr, nullptr, aqb, aa_wa, ascore);
  softmax_his<<<32, 256, 0, stream>>>(ascore, his_mask);
  hw_kernel<<<dim3(8, 32), 256, 0, stream>>>(ascore, hisb, hwb);
  gemv32<<<dim3(4, 32), 256, 0, stream>>>(hwb, aa_wv, actx);
  gemv32<<<dim3(4, 32), 256, 0, stream>>>(actx, aa_wo, aaout);
  final_kernel<<<32, 256, 0, stream>>>(aaout, ln_g, ln_b, poi, out);
}

// Round 6
// 784.319 us; speedup vs baseline: 1.0234x; 1.0234x over previous
//
#include <hip/hip_runtime.h>

#define NEGV (-1000000000.0f)

typedef __attribute__((ext_vector_type(8))) short sh8;
typedef __attribute__((ext_vector_type(4))) short sh4;
typedef __attribute__((ext_vector_type(8))) __bf16 bf16x8;
typedef __attribute__((ext_vector_type(4))) float f32x4;

__device__ __forceinline__ float b2f(unsigned short u) {
  unsigned v = ((unsigned)u) << 16;
  return __builtin_bit_cast(float, v);
}
__device__ __forceinline__ unsigned short f2b(float f) {
  unsigned x = __builtin_bit_cast(unsigned, f);
  unsigned r = (x + 0x7fffu + ((x >> 16) & 1u)) >> 16;
  return (unsigned short)r;
}
__device__ __forceinline__ void g2l16(const void* g, void* l) {
  __builtin_amdgcn_global_load_lds((const __attribute__((address_space(1))) unsigned int*)g,
                                   (__attribute__((address_space(3))) unsigned int*)l, 16, 0, 0);
}
__device__ __forceinline__ f32x4 mfma16(bf16x8 a, bf16x8 b, f32x4 c) {
  return __builtin_amdgcn_mfma_f32_16x16x32_bf16(a, b, c, 0, 0, 0);
}
__device__ __forceinline__ float fast_tanh(float x) {
  x = fminf(fmaxf(x, -15.f), 15.f);
  float e = __expf(2.f * x);
  return (e - 1.f) / (e + 1.f);
}

// ---------------- conversion kernels ----------------
__global__ void cvt_bf16(const float* __restrict__ src, unsigned short* __restrict__ dst, int n4) {
  int i = blockIdx.x * blockDim.x + threadIdx.x;
  int stride = gridDim.x * blockDim.x;
  for (; i < n4; i += stride) {
    float4 v = ((const float4*)src)[i];
    sh4 o;
    o[0] = (short)f2b(v.x); o[1] = (short)f2b(v.y);
    o[2] = (short)f2b(v.z); o[3] = (short)f2b(v.w);
    ((sh4*)dst)[i] = o;
  }
}

// dst[n][k] = bf16(src[k][n]) for 1024x1024
__global__ void tcvt(const float* __restrict__ src, unsigned short* __restrict__ dst) {
  __shared__ float tile[64][65];
  int bx = blockIdx.x, by = blockIdx.y;
  int tx = threadIdx.x & 63, ty = threadIdx.x >> 6;
#pragma unroll
  for (int i = 0; i < 16; ++i) {
    int r = i * 4 + ty;
    tile[r][tx] = src[(size_t)(by * 64 + r) * 1024 + bx * 64 + tx];
  }
  __syncthreads();
#pragma unroll
  for (int i = 0; i < 16; ++i) {
    int r = i * 4 + ty;
    dst[(size_t)(bx * 64 + r) * 1024 + by * 64 + tx] = f2b(tile[tx][r]);
  }
}

// ---------------- 256x256 bf16 MFMA GEMM, K=1024, 8-phase m201-style ----------------
// BK=64, 16 K-steps, 2 per iteration. LDS: 2 buffers x 64KB
//   buf layout: A0 @0 (tile rows 0-127), A1 @16K, B0 @32K, B1 @48K; row=64k=128B.
//   granule = 8KB (64 rows): {half, rowhalf}. Stage = 1 g2l16 per wave per granule.
// Per phase: {4-8 ds_read_b128; 2 granule stages; sched_barrier; s_barrier;
//   lgkmcnt(0)+sched_barrier; setprio(1); 16 MFMA; setprio(0); [vmcnt]; s_barrier}
// Phase p: quadrant (ks=(p>>1)&1, ih=p&1) of K-step 2t (p<4, buf0) / 2t+1 (buf1).
// Stages: p0:A?H'(k1) p1:B0'(k1) p2:B1'(k1) p3:A?L(k2) p4:A?H(k2) p5:B0(k2)
//         p6:B1(k2) p7:A?L'(k3).  vmcnt(2) at end of p3 and p7 only.
// Chunk swizzle (verified 0-conflict in r4): LDS chunk c of row r holds global
// chunk c^(r&7); reads use chunk ((ks*4+g)^(lr&7)).
template<int EPI>
__global__ __launch_bounds__(512, 1)
void gemm256(const unsigned short* __restrict__ A, const unsigned short* __restrict__ Bt,
             int nbx,
             const float* __restrict__ b0, const float* __restrict__ b1,
             const float* __restrict__ b2,
             unsigned short* __restrict__ O0, unsigned short* __restrict__ O1,
             unsigned short* __restrict__ O2,
             const float* __restrict__ aq, const float* __restrict__ wa,
             float* __restrict__ sc)
{
  __shared__ char lds[131072];
  const int tid = threadIdx.x;
  const int w = tid >> 6, l = tid & 63;
  const int wm = w >> 2, wn = w & 3;
  const int lr = l & 15, g = l >> 4;

  // bijective XCD swizzle (gridDim.x % 8 == 0 for all our shapes)
  const int wg = blockIdx.x;
  const int cpx = gridDim.x >> 3;
  const int wgid = (wg & 7) * cpx + (wg >> 3);
  const int bx = wgid % nbx, by = wgid / nbx;
  const size_t m0 = (size_t)by * 256;
  const int n0 = bx * 256;

  f32x4 acc[8][4] = {};
  bf16x8 fa[4], fb[4];

  // staging: lane covers row (w*8 + (l>>3)) of a 64-row granule, 16B chunk (l&7)
  // pre-swizzled global source chunk = (l&7)^((l>>3)&7)
  const int srow = w * 8 + (l >> 3);
  const int schunk = ((l & 7) ^ ((l >> 3) & 7)) * 8;
  const unsigned short* gA = A + (m0 + srow) * 1024 + schunk;
  const unsigned short* gB = Bt + ((size_t)n0 + srow) * 1024 + schunk;
  const int ldst = w * 1024;  // wave-uniform LDS offset; HW adds lane*16

  // read offsets (bytes within a 64KB buffer)
  const int chs = lr & 7;
  const int aRd0 = wm * 16384 + lr * 128;                              // +ih*8192 +i*2048 +ck
  const int bRd0 = 32768 + (wn >> 1) * 16384 + (wn & 1) * 8192 + lr * 128;  // +j*2048 +ck
  const int ck0 = ((0 * 4 + g) ^ chs) * 16;
  const int ck1 = ((1 * 4 + g) ^ chs) * 16;

#define STG_A(BUF, AH, RH, KK) \
  g2l16(gA + ((AH) * 128 + (RH) * 64) * 1024 + (KK), \
        lds + (BUF) * 65536 + (AH) * 16384 + (RH) * 8192 + ldst)
#define STG_B(BUF, BH, RH, KK) \
  g2l16(gB + ((BH) * 128 + (RH) * 64) * 1024 + (KK), \
        lds + (BUF) * 65536 + 32768 + (BH) * 16384 + (RH) * 8192 + ldst)

#define PH(BUFOFF, CK, IH, STAGES, TAIL)                                      \
  {                                                                           \
    const char* pb_ = lds + (BUFOFF);                                         \
    if ((IH) == 0) {                                                          \
      _Pragma("unroll") for (int j = 0; j < 4; ++j)                           \
        fb[j] = *(const bf16x8*)(pb_ + bRd0 + j * 2048 + (CK));               \
    }                                                                         \
    _Pragma("unroll") for (int i = 0; i < 4; ++i)                             \
      fa[i] = *(const bf16x8*)(pb_ + aRd0 + (IH) * 8192 + i * 2048 + (CK));   \
    STAGES;                                                                   \
    __builtin_amdgcn_sched_barrier(0);                                        \
    asm volatile("s_barrier" ::: "memory");                                   \
    asm volatile("s_waitcnt lgkmcnt(0)" ::: "memory");                        \
    __builtin_amdgcn_sched_barrier(0);                                        \
    __builtin_amdgcn_s_setprio(1);                                            \
    _Pragma("unroll") for (int i = 0; i < 4; ++i)                             \
      _Pragma("unroll") for (int j = 0; j < 4; ++j)                           \
        acc[(IH) * 4 + i][j] = mfma16(fa[i], fb[j], acc[(IH) * 4 + i][j]);    \
    __builtin_amdgcn_s_setprio(0);                                            \
    TAIL;                                                                     \
    asm volatile("s_barrier" ::: "memory");                                   \
  }

  // ---- prologue: buf0 <- K-step 0 (8 granules), buf1 <- K-step 1 A?L ----
  STG_A(0, 0, 0, 0); STG_A(0, 0, 1, 0); STG_A(0, 1, 0, 0); STG_A(0, 1, 1, 0);
  STG_B(0, 0, 0, 0); STG_B(0, 0, 1, 0); STG_B(0, 1, 0, 0); STG_B(0, 1, 1, 0);
  STG_A(1, 0, 0, 64); STG_A(1, 1, 0, 64);
  asm volatile("s_waitcnt vmcnt(0)" ::: "memory");
  asm volatile("s_barrier" ::: "memory");

#pragma unroll 1
  for (int t = 0; t < 8; ++t) {
    const int k1 = (2 * t + 1) * 64, k2 = (2 * t + 2) * 64, k3 = (2 * t + 3) * 64;
    const bool st = (t < 7);
    PH(0,     ck0, 0, { STG_A(1, 0, 1, k1); STG_A(1, 1, 1, k1); }, {})
    PH(0,     ck0, 1, { STG_B(1, 0, 0, k1); STG_B(1, 0, 1, k1); }, {})
    PH(0,     ck1, 0, { STG_B(1, 1, 0, k1); STG_B(1, 1, 1, k1); }, {})
    PH(0,     ck1, 1, { if (st) { STG_A(0, 0, 0, k2); STG_A(0, 1, 0, k2); } },
       { if (st) { asm volatile("s_waitcnt vmcnt(2)" ::: "memory"); }
         else    { asm volatile("s_waitcnt vmcnt(0)" ::: "memory"); } })
    PH(65536, ck0, 0, { if (st) { STG_A(0, 0, 1, k2); STG_A(0, 1, 1, k2); } }, {})
    PH(65536, ck0, 1, { if (st) { STG_B(0, 0, 0, k2); STG_B(0, 0, 1, k2); } }, {})
    PH(65536, ck1, 0, { if (st) { STG_B(0, 1, 0, k2); STG_B(0, 1, 1, k2); } }, {})
    PH(65536, ck1, 1, { if (st) { STG_A(1, 0, 0, k3); STG_A(1, 1, 0, k3); } },
       { if (st) { asm volatile("s_waitcnt vmcnt(2)" ::: "memory"); } })
  }
#undef PH
#undef STG_A
#undef STG_B

  // ======== epilogue ========
  if (EPI == 0) {
#pragma unroll
    for (int j = 0; j < 4; ++j) {
      int col = n0 + wn * 64 + j * 16 + lr;
      float bv = b0[col];
#pragma unroll
      for (int i = 0; i < 8; ++i) {
        size_t rowb = m0 + wm * 128 + i * 16 + g * 4;
#pragma unroll
        for (int r = 0; r < 4; ++r)
          O0[(rowb + r) * 1024 + col] = f2b(acc[i][j][r] + bv);
      }
    }
  } else if (EPI == 1) {
#pragma unroll
    for (int j = 0; j < 4; ++j) {
      int col3 = n0 + wn * 64 + j * 16 + lr;
      int part = col3 >> 10, c = col3 & 1023;
      float bv = (part == 0) ? b0[c] : (part == 1) ? b1[c] : b2[c];
      if (part < 2) {
        unsigned short* O = part == 0 ? O0 : O1;
#pragma unroll
        for (int i = 0; i < 8; ++i) {
          size_t rowb = m0 + wm * 128 + i * 16 + g * 4;
#pragma unroll
          for (int r = 0; r < 4; ++r)
            O[(rowb + r) * 1024 + c] = f2b(acc[i][j][r] + bv);
        }
      } else {  // v: transposed layout vT[(b*4+h)*256 + d][512] = v[b, l, h, d]
        int h = c >> 8, d = c & 255;
#pragma unroll
        for (int i = 0; i < 8; ++i) {
          size_t row = m0 + wm * 128 + i * 16 + g * 4;
          int bb = (int)(row >> 9), ll = (int)(row & 511);
          size_t base = ((size_t)(bb * 4 + h) * 256 + d) * 512 + ll;
#pragma unroll
          for (int r = 0; r < 4; ++r)
            O2[base + r] = f2b(acc[i][j][r] + bv);
        }
      }
    }
  } else {
    const int bb = (int)(m0 >> 11);
#pragma unroll
    for (int i = 0; i < 8; ++i) {
      float rp[4] = {0.f, 0.f, 0.f, 0.f};
#pragma unroll
      for (int j = 0; j < 4; ++j) {
        int col = n0 + wn * 64 + j * 16 + lr;
        float wav = wa[col];
        float aqv = aq[bb * 1024 + col];
#pragma unroll
        for (int r = 0; r < 4; ++r)
          rp[r] += wav * fast_tanh(acc[i][j][r] + aqv);
      }
#pragma unroll
      for (int off = 1; off < 16; off <<= 1)
#pragma unroll
        for (int r = 0; r < 4; ++r)
          rp[r] += __shfl_xor(rp[r], off, 64);
      if (lr == 0) {
        size_t rowb = m0 + wm * 128 + i * 16 + g * 4;
#pragma unroll
        for (int r = 0; r < 4; ++r)
          atomicAdd(&sc[rowb + r], rp[r]);
      }
    }
  }
}

// ---------------- fused attention (register softmax, 34.3KB LDS) ----------------
__global__ __launch_bounds__(256, 4)
void attn_kernel(const unsigned short* __restrict__ q, const unsigned short* __restrict__ k,
                 const unsigned short* __restrict__ vT, const float* __restrict__ seq_mask,
                 unsigned short* __restrict__ ctx, float* __restrict__ attn_out)
{
  __shared__ char smem[34304];
  unsigned short* Qs = (unsigned short*)smem;
  unsigned short* Ps = (unsigned short*)smem;
  float* redm = (float*)(smem + 33280);
  float* reds = (float*)(smem + 33792);
  const int t = threadIdx.x, w = t >> 6, l = t & 63;
  const int lr = l & 15, g = l >> 4, lk8 = g * 8;
  const int wg = blockIdx.x;
  const int wgid = (wg & 7) * 256 + (wg >> 3);
  const int qt = wgid & 15, bh = wgid >> 4;
  const int h = bh & 3, b = bh >> 2;
  const int l0 = qt * 32;

  for (int idx = t; idx < 32 * 32; idx += 256) {
    int r = idx >> 5, ch = (idx & 31) * 8;
    *(sh8*)&Qs[r * 264 + ch] =
        *(const sh8*)&q[((size_t)(b * 512 + l0 + r)) * 1024 + h * 256 + ch];
  }
  __syncthreads();

  f32x4 accs[2][8] = {};
  const unsigned short* kbase = k + ((size_t)b * 512) * 1024 + h * 256;
#pragma unroll
  for (int ds = 0; ds < 8; ++ds) {
    int d0 = ds * 32;
    bf16x8 a0 = *(const bf16x8*)&Qs[lr * 264 + d0 + lk8];
    bf16x8 a1 = *(const bf16x8*)&Qs[(16 + lr) * 264 + d0 + lk8];
#pragma unroll
    for (int j = 0; j < 8; ++j) {
      int kj = w * 128 + j * 16 + lr;
      bf16x8 bb = *(const bf16x8*)&kbase[(size_t)kj * 1024 + d0 + lk8];
      accs[0][j] = mfma16(a0, bb, accs[0][j]);
      accs[1][j] = mfma16(a1, bb, accs[1][j]);
    }
  }

#pragma unroll
  for (int j = 0; j < 8; ++j) {
    int col = w * 128 + j * 16 + lr;
    float mv = seq_mask[b * 512 + col];
    bool msk = (mv == 0.f);
#pragma unroll
    for (int i = 0; i < 2; ++i)
#pragma unroll
      for (int r = 0; r < 4; ++r)
        accs[i][j][r] = msk ? NEGV : accs[i][j][r] * 0.0625f;
  }

  float mx[2][4], sm[2][4];
#pragma unroll
  for (int i = 0; i < 2; ++i)
#pragma unroll
    for (int r = 0; r < 4; ++r) {
      float m = accs[i][0][r];
#pragma unroll
      for (int j = 1; j < 8; ++j) m = fmaxf(m, accs[i][j][r]);
      mx[i][r] = m;
    }
#pragma unroll
  for (int off = 1; off < 16; off <<= 1)
#pragma unroll
    for (int i = 0; i < 2; ++i)
#pragma unroll
      for (int r = 0; r < 4; ++r)
        mx[i][r] = fmaxf(mx[i][r], __shfl_xor(mx[i][r], off, 64));
  if (lr == 0) {
#pragma unroll
    for (int i = 0; i < 2; ++i)
#pragma unroll
      for (int r = 0; r < 4; ++r)
        redm[w * 32 + i * 16 + g * 4 + r] = mx[i][r];
  }
  __syncthreads();
#pragma unroll
  for (int i = 0; i < 2; ++i)
#pragma unroll
    for (int r = 0; r < 4; ++r) {
      int row = i * 16 + g * 4 + r;
      mx[i][r] = fmaxf(fmaxf(redm[row], redm[32 + row]),
                       fmaxf(redm[64 + row], redm[96 + row]));
      sm[i][r] = 0.f;
    }

#pragma unroll
  for (int i = 0; i < 2; ++i)
#pragma unroll
    for (int j = 0; j < 8; ++j)
#pragma unroll
      for (int r = 0; r < 4; ++r) {
        float p = __expf(accs[i][j][r] - mx[i][r]);
        accs[i][j][r] = p;
        sm[i][r] += p;
      }
#pragma unroll
  for (int off = 1; off < 16; off <<= 1)
#pragma unroll
    for (int i = 0; i < 2; ++i)
#pragma unroll
      for (int r = 0; r < 4; ++r)
        sm[i][r] += __shfl_xor(sm[i][r], off, 64);
  if (lr == 0) {
#pragma unroll
    for (int i = 0; i < 2; ++i)
#pragma unroll
      for (int r = 0; r < 4; ++r)
        reds[w * 32 + i * 16 + g * 4 + r] = sm[i][r];
  }
  __syncthreads();
#pragma unroll
  for (int i = 0; i < 2; ++i)
#pragma unroll
    for (int r = 0; r < 4; ++r) {
      int row = i * 16 + g * 4 + r;
      float s = reds[row] + reds[32 + row] + reds[64 + row] + reds[96 + row];
      sm[i][r] = 1.f / s;
    }

#pragma unroll
  for (int i = 0; i < 2; ++i)
#pragma unroll
    for (int j = 0; j < 8; ++j) {
      int col = w * 128 + j * 16 + lr;
#pragma unroll
      for (int r = 0; r < 4; ++r) {
        int row = i * 16 + g * 4 + r;
        float pn = accs[i][j][r] * sm[i][r];
        Ps[row * 520 + col] = f2b(pn);
        if (h == 0)
          attn_out[((size_t)(b * 512 + l0 + row)) * 512 + col] = pn;
      }
    }
  __syncthreads();

  f32x4 acco[2][4] = {};
  const unsigned short* vbase = vT + ((size_t)(b * 4 + h)) * 256 * 512;
#pragma unroll
  for (int ks = 0; ks < 16; ++ks) {
    int kj0 = ks * 32;
    bf16x8 a0 = *(const bf16x8*)&Ps[lr * 520 + kj0 + lk8];
    bf16x8 a1 = *(const bf16x8*)&Ps[(16 + lr) * 520 + kj0 + lk8];
#pragma unroll
    for (int j = 0; j < 4; ++j) {
      int d = w * 64 + j * 16 + lr;
      bf16x8 bb = *(const bf16x8*)&vbase[(size_t)d * 512 + kj0 + lk8];
      acco[0][j] = mfma16(a0, bb, acco[0][j]);
      acco[1][j] = mfma16(a1, bb, acco[1][j]);
    }
  }
#pragma unroll
  for (int i = 0; i < 2; ++i)
#pragma unroll
    for (int j = 0; j < 4; ++j) {
      int col = w * 64 + j * 16 + lr;
#pragma unroll
      for (int r = 0; r < 4; ++r) {
        int row = i * 16 + g * 4 + r;
        ctx[((size_t)(b * 512 + l0 + row)) * 1024 + h * 256 + col] = f2b(acco[i][j][r]);
      }
    }
}

// ---------------- LN + masked mean over L ----------------
__global__ __launch_bounds__(256)
void ln_mean(const unsigned short* __restrict__ sa, const float* __restrict__ g,
             const float* __restrict__ bt, const float* __restrict__ mask,
             float* __restrict__ poi_sum)
{
  const int b = blockIdx.y, ch = blockIdx.x;
  const int t = threadIdx.x, w = t >> 6, l = t & 63;
  float gg[16], bb[16];
#pragma unroll
  for (int j = 0; j < 16; ++j) { gg[j] = g[l * 16 + j]; bb[j] = bt[l * 16 + j]; }
  float accv[16];
#pragma unroll
  for (int j = 0; j < 16; ++j) accv[j] = 0.f;
  for (int rr = 0; rr < 16; ++rr) {
    int row = ch * 64 + w * 16 + rr;
    const unsigned short* rp = sa + ((size_t)(b * 512 + row)) * 1024 + l * 16;
    float x[16];
    sh8 v0 = *(const sh8*)rp;
    sh8 v1 = *(const sh8*)(rp + 8);
#pragma unroll
    for (int j = 0; j < 8; ++j) {
      x[j] = b2f((unsigned short)v0[j]);
      x[8 + j] = b2f((unsigned short)v1[j]);
    }
    float s = 0.f, s2 = 0.f;
#pragma unroll
    for (int j = 0; j < 16; ++j) { s += x[j]; s2 += x[j] * x[j]; }
#pragma unroll
    for (int off = 1; off < 64; off <<= 1) {
      s += __shfl_xor(s, off, 64);
      s2 += __shfl_xor(s2, off, 64);
    }
    float mean = s * (1.f / 1024.f);
    float var = s2 * (1.f / 1024.f) - mean * mean;
    float rinv = rsqrtf(var + 1e-5f);
    float mk = mask[b * 512 + row];
#pragma unroll
    for (int j = 0; j < 16; ++j) accv[j] += ((x[j] - mean) * rinv * gg[j] + bb[j]) * mk;
  }
#pragma unroll
  for (int j = 0; j < 16; ++j) atomicAdd(&poi_sum[b * 1024 + l * 16 + j], accv[j]);
}

__global__ void finalize_poi(const float* __restrict__ ps, float* __restrict__ poi) {
  int i = blockIdx.x * 256 + threadIdx.x;
  if (i < 32 * 1024) poi[i] = ps[i] * (1.f / 512.f);
}

__global__ __launch_bounds__(256)
void gemv32(const float* __restrict__ in, const float* __restrict__ W, float* __restrict__ out)
{
  const int b = blockIdx.y;
  const int n = blockIdx.x * 256 + threadIdx.x;
  const float* ib = in + b * 1024;
  float acc = 0.f;
  for (int d = 0; d < 1024; d += 4) {
    acc += ib[d]     * W[(size_t)d * 1024 + n]
         + ib[d + 1] * W[(size_t)(d + 1) * 1024 + n]
         + ib[d + 2] * W[(size_t)(d + 2) * 1024 + n]
         + ib[d + 3] * W[(size_t)(d + 3) * 1024 + n];
  }
  out[b * 1024 + n] = acc;
}

__global__ __launch_bounds__(256)
void softmax_his(float* __restrict__ sc, const float* __restrict__ mask)
{
  __shared__ float red[4];
  const int b = blockIdx.x, t = threadIdx.x, w = t >> 6, l = t & 63;
  float v[8];
  float mx = -3.0e38f;
#pragma unroll
  for (int i = 0; i < 8; ++i) {
    int kk = t + i * 256;
    float s = (mask[b * 2048 + kk] == 0.f) ? NEGV : sc[b * 2048 + kk];
    v[i] = s;
    mx = fmaxf(mx, s);
  }
#pragma unroll
  for (int off = 1; off < 64; off <<= 1) mx = fmaxf(mx, __shfl_xor(mx, off, 64));
  if (l == 0) red[w] = mx;
  __syncthreads();
  mx = fmaxf(fmaxf(red[0], red[1]), fmaxf(red[2], red[3]));
  float sum = 0.f;
#pragma unroll
  for (int i = 0; i < 8; ++i) { v[i] = __expf(v[i] - mx); sum += v[i]; }
#pragma unroll
  for (int off = 1; off < 64; off <<= 1) sum += __shfl_xor(sum, off, 64);
  __syncthreads();
  if (l == 0) red[w] = sum;
  __syncthreads();
  sum = red[0] + red[1] + red[2] + red[3];
  float inv = 1.f / sum;
#pragma unroll
  for (int i = 0; i < 8; ++i) sc[b * 2048 + t + i * 256] = v[i] * inv;
}

__global__ __launch_bounds__(256)
void hw_kernel(const float* __restrict__ aw, const unsigned short* __restrict__ his,
               float* __restrict__ hw)
{
  const int b = blockIdx.y, kc = blockIdx.x, t = threadIdx.x;
  const int cb = t * 4;
  float a0 = 0.f, a1 = 0.f, a2 = 0.f, a3 = 0.f;
  for (int kk = 0; kk < 256; ++kk) {
    int k = kc * 256 + kk;
    float wg = aw[b * 2048 + k];
    sh4 vv = *(const sh4*)&his[((size_t)(b * 2048 + k)) * 1024 + cb];
    a0 += wg * b2f((unsigned short)vv[0]);
    a1 += wg * b2f((unsigned short)vv[1]);
    a2 += wg * b2f((unsigned short)vv[2]);
    a3 += wg * b2f((unsigned short)vv[3]);
  }
  atomicAdd(&hw[b * 1024 + cb + 0], a0);
  atomicAdd(&hw[b * 1024 + cb + 1], a1);
  atomicAdd(&hw[b * 1024 + cb + 2], a2);
  atomicAdd(&hw[b * 1024 + cb + 3], a3);
}

__global__ __launch_bounds__(256)
void final_kernel(const float* __restrict__ aa_out, const float* __restrict__ g,
                  const float* __restrict__ bt, const float* __restrict__ poi,
                  float* __restrict__ out)
{
  __shared__ float r1[4], r2[4];
  const int b = blockIdx.x, t = threadIdx.x, w = t >> 6, l = t & 63;
  float x[4];
#pragma unroll
  for (int j = 0; j < 4; ++j) x[j] = aa_out[b * 1024 + t * 4 + j];
  float s = 0.f, s2 = 0.f;
#pragma unroll
  for (int j = 0; j < 4; ++j) { s += x[j]; s2 += x[j] * x[j]; }
#pragma unroll
  for (int off = 1; off < 64; off <<= 1) {
    s += __shfl_xor(s, off, 64);
    s2 += __shfl_xor(s2, off, 64);
  }
  if (l == 0) { r1[w] = s; r2[w] = s2; }
  __syncthreads();
  s = r1[0] + r1[1] + r1[2] + r1[3];
  s2 = r2[0] + r2[1] + r2[2] + r2[3];
  float mean = s * (1.f / 1024.f);
  float var = s2 * (1.f / 1024.f) - mean * mean;
  float rinv = rsqrtf(var + 1e-5f);
#pragma unroll
  for (int j = 0; j < 4; ++j) {
    int c = t * 4 + j;
    float lnv = (x[j] - mean) * rinv * g[c] + bt[c];
    float pv = poi[b * 1024 + c];
    out[b * 2048 + c] = pv;
    out[b * 2048 + 1024 + c] = pv + lnv;
  }
}

// ---------------- host launch ----------------
extern "C" void kernel_launch(void* const* d_in, const int* in_sizes, int n_in,
                              void* d_out, int out_size, void* d_ws, size_t ws_size,
                              hipStream_t stream)
{
  const float* seq_emb  = (const float*)d_in[0];
  const float* seq_mask = (const float*)d_in[1];
  const float* his_emb  = (const float*)d_in[2];
  const float* his_mask = (const float*)d_in[3];
  const float* sa_wq = (const float*)d_in[4];
  const float* sa_bq = (const float*)d_in[5];
  const float* sa_wk = (const float*)d_in[6];
  const float* sa_bk = (const float*)d_in[7];
  const float* sa_wv = (const float*)d_in[8];
  const float* sa_bv = (const float*)d_in[9];
  const float* sa_wo = (const float*)d_in[10];
  const float* sa_bo = (const float*)d_in[11];
  const float* sn_g  = (const float*)d_in[12];
  const float* sn_b  = (const float*)d_in[13];
  const float* aa_wq = (const float*)d_in[14];
  const float* aa_wk = (const float*)d_in[15];
  const float* aa_wv = (const float*)d_in[16];
  const float* aa_wo = (const float*)d_in[17];
  const float* aa_wa = (const float*)d_in[18];
  const float* ln_g  = (const float*)d_in[19];
  const float* ln_b  = (const float*)d_in[20];
  float* out = (float*)d_out;

  char* p = (char*)d_ws;
  size_t off = 0;
  auto alloc = [&](size_t bytes) -> void* {
    void* r = p + off;
    off += (bytes + 255) & ~(size_t)255;
    return r;
  };
  unsigned short* seqb = (unsigned short*)alloc((size_t)16384 * 1024 * 2);
  unsigned short* hisb = (unsigned short*)alloc((size_t)65536 * 1024 * 2);
  unsigned short* wcat = (unsigned short*)alloc((size_t)3072 * 1024 * 2);
  unsigned short* woT  = (unsigned short*)alloc((size_t)1024 * 1024 * 2);
  unsigned short* awkT = (unsigned short*)alloc((size_t)1024 * 1024 * 2);
  unsigned short* qb   = (unsigned short*)alloc((size_t)16384 * 1024 * 2);
  unsigned short* kb   = (unsigned short*)alloc((size_t)16384 * 1024 * 2);
  unsigned short* vTb  = (unsigned short*)alloc((size_t)16384 * 1024 * 2);
  unsigned short* ctxb = (unsigned short*)alloc((size_t)16384 * 1024 * 2);
  unsigned short* saob = (unsigned short*)alloc((size_t)16384 * 1024 * 2);
  float* poi_sum = (float*)alloc((size_t)32 * 1024 * 4);
  float* poi     = (float*)alloc((size_t)32 * 1024 * 4);
  float* aqb     = (float*)alloc((size_t)32 * 1024 * 4);
  float* ascore  = (float*)alloc((size_t)32 * 2048 * 4);
  float* hwb     = (float*)alloc((size_t)32 * 1024 * 4);
  float* actx    = (float*)alloc((size_t)32 * 1024 * 4);
  float* aaout   = (float*)alloc((size_t)32 * 1024 * 4);
  if (off > ws_size) return;

  hipMemsetAsync(poi_sum, 0, (size_t)32 * 1024 * 4, stream);
  hipMemsetAsync(ascore, 0, (size_t)32 * 2048 * 4, stream);
  hipMemsetAsync(hwb, 0, (size_t)32 * 1024 * 4, stream);

  cvt_bf16<<<2048, 256, 0, stream>>>(seq_emb, seqb, 16384 * 1024 / 4);
  cvt_bf16<<<2048, 256, 0, stream>>>(his_emb, hisb, 65536 * 1024 / 4);
  dim3 tg(16, 16);
  tcvt<<<tg, 256, 0, stream>>>(sa_wq, wcat);
  tcvt<<<tg, 256, 0, stream>>>(sa_wk, wcat + (size_t)1024 * 1024);
  tcvt<<<tg, 256, 0, stream>>>(sa_wv, wcat + (size_t)2048 * 1024);
  tcvt<<<tg, 256, 0, stream>>>(sa_wo, woT);
  tcvt<<<tg, 256, 0, stream>>>(aa_wk, awkT);

  // fused QKV: M=16384, N=3072 -> 64 x 12 = 768 blocks
  gemm256<1><<<768, 512, 0, stream>>>(seqb, wcat, 12, sa_bq, sa_bk, sa_bv,
                                      qb, kb, vTb, nullptr, nullptr, nullptr);

  attn_kernel<<<2048, 256, 0, stream>>>(qb, kb, vTb, seq_mask, ctxb, out + 65536);

  // sa_out: M=16384, N=1024 -> 64 x 4 = 256 blocks
  gemm256<0><<<256, 512, 0, stream>>>(ctxb, woT, 4, sa_bo, nullptr, nullptr,
                                      saob, nullptr, nullptr, nullptr, nullptr, nullptr);
  ln_mean<<<dim3(8, 32), 256, 0, stream>>>(saob, sn_g, sn_b, seq_mask, poi_sum);
  finalize_poi<<<128, 256, 0, stream>>>(poi_sum, poi);
  gemv32<<<dim3(4, 32), 256, 0, stream>>>(poi, aa_wq, aqb);

  // his scores: M=65536, N=1024 -> 256 x 4 = 1024 blocks
  gemm256<2><<<1024, 512, 0, stream>>>(hisb, awkT, 4, nullptr, nullptr, nullptr,
                                       nullptr, nullptr, nullptr, aqb, aa_wa, ascore);
  softmax_his<<<32, 256, 0, stream>>>(ascore, his_mask);
  hw_kernel<<<dim3(8, 32), 256, 0, stream>>>(ascore, hisb, hwb);
  gemv32<<<dim3(4, 32), 256, 0, stream>>>(hwb, aa_wv, actx);
  gemv32<<<dim3(4, 32), 256, 0, stream>>>(actx, aa_wo, aaout);
  final_kernel<<<32, 256, 0, stream>>>(aaout, ln_g, ln_b, poi, out);
}